// Round 5
// baseline (268.055 us; speedup 1.0000x reference)
//
#include <hip/hip_runtime.h>
#include <math.h>

// HuberEMA: y[t] = y[t-1] + (1-a[c]) * clamp(x[t]-y[t-1], -d, +d); y[0] = x[0]
// B=32, T=2048, C=512 fp32. 16384 chains -> 256 blocks x 64 lanes (1 wave/CU).
// Roofline: 268 MB => ~43 us @ 6.3 TB/s.
//
// R4 post-mortem: 107 us, VGPR=88 => compiler sank the 64 per-tile ds_reads
// into the serial recurrence (xin never materialized) -> ~120 cyc single-
// outstanding LDS latency per timestep = 102 us. Also 80 VMEM ops/tile
// (64 scalar y stores + 16 loads) > 63-deep vmcnt queue.
//
// Fix 1: sched_barrier(0) after the batched xin read loop — pins all 64
//        ds_read_b32 before the compute chain (pipelined ~5.8 cyc/op).
// Fix 2: y repacked through LDS -> 16 global dwordx4 stores per tile
//        (32 VMEM ops/tile total; prefetch distance-2 ~1700 cyc > HBM lat).
//
// Per 64-t tile (per wave):
//   64 ds_read_b32 xin  | stage k+1: 16 ds_write_b128 | prefetch k+2: 16 ldx4
//   -> 64-step recurrence, y -> LDS scalar (conflict-free)
//   -> 16 ds_read_b128 repack -> 16 global dwordx4 stores (1 KB/instr).
// All register arrays statically indexed (full unroll) - no scratch.

#define TT   2048
#define CC   512
#define TILE 64
#define NTIL (TT / TILE)   // 32 tiles

__global__ __launch_bounds__(64, 1)
void huber_ema_kernel(const float* __restrict__ x,
                      const float* __restrict__ logit_alpha,
                      const float* __restrict__ delta,
                      float* __restrict__ y)
{
    const int blk  = blockIdx.x;     // 0..255
    const int b    = blk >> 3;       // batch
    const int cc   = blk & 7;        // 64-wide channel chunk
    const int lane = threadIdx.x;    // 0..63

    // per-chain alpha: a = clip(sigmoid(la), 1e-4, 1-1e-4)
    const float la = logit_alpha[(cc << 6) + lane];
    float a = 1.0f / (1.0f + expf(-la));
    a = fminf(fmaxf(a, 1e-4f), 1.0f - 1e-4f);
    const float oma = 1.0f - a;
    const float d = delta[0];

    const float* __restrict__ xb = x + (size_t)b * TT * CC + (cc << 6);
    float*       __restrict__ yb = y + (size_t)b * TT * CC + (cc << 6);

    // packed x4 mapping: lane covers t_loc = g*4 + (lane>>4),
    // channels (lane&15)*4 .. +3
    const int tl = lane >> 4;
    const int c4 = (lane & 15) << 2;
    const float* __restrict__ xl = xb + (size_t)tl * CC + c4;
    float*       __restrict__ yl = yb + (size_t)tl * CC + c4;

    // [t_in_tile][ch] tiles, double-buffered: x 2x16KB + y 2x16KB = 64 KB
    __shared__ float xs[2][TILE * 64];
    __shared__ float ys[2][TILE * 64];

    float4 xr[16];     // in-flight prefetch tile (1 KB per wave-instruction)

    // y chain init: yv = x[t=0]; tile-0 step 0 computes r=0 -> y0 = x0 exactly
    float yv = xb[lane];

    // prologue: tile 0 -> regs -> xs[0]; tile 1 -> xr
    {
        float4 t0[16];
        #pragma unroll
        for (int g = 0; g < 16; ++g)
            t0[g] = *(const float4*)(xl + (size_t)(g * 4) * CC);
        #pragma unroll
        for (int g = 0; g < 16; ++g)
            *(float4*)&xs[0][g * 256 + (lane << 2)] = t0[g];
    }
    #pragma unroll
    for (int g = 0; g < 16; ++g)
        xr[g] = *(const float4*)(xl + (size_t)(TILE + g * 4) * CC);

    for (int k = 0; k < NTIL; ++k) {
        const float* __restrict__ bx  = xs[k & 1];        // tile k inputs
        float*       __restrict__ bxn = xs[(k + 1) & 1];  // stage target
        float*       __restrict__ by  = ys[k & 1];        // y repack buffer

        // 1) batch-issue ALL 64 xin reads; sched_barrier pins them ahead of
        //    the serial chain so they pipeline (~5.8 cyc/op) instead of
        //    paying ~120 cyc single-outstanding latency per step.
        float xin[TILE];
        #pragma unroll
        for (int i = 0; i < TILE; ++i)
            xin[i] = bx[i * 64 + lane];
        __builtin_amdgcn_sched_barrier(0);

        // 2) stage tile k+1 regs -> LDS (vmcnt-waits on its global loads,
        //    issued a full tile ago)   3) issue tile k+2 global loads
        if (k + 1 < NTIL) {
            #pragma unroll
            for (int g = 0; g < 16; ++g)
                *(float4*)&bxn[g * 256 + (lane << 2)] = xr[g];
        }
        if (k + 2 < NTIL) {
            #pragma unroll
            for (int g = 0; g < 16; ++g)
                xr[g] = *(const float4*)(xl + (size_t)((k + 2) * TILE + g * 4) * CC);
        }
        __builtin_amdgcn_sched_barrier(0);

        // 4) recurrence; y -> LDS scalar (64 consecutive words/wave = free)
        #pragma unroll
        for (int i = 0; i < TILE; ++i) {
            float r = xin[i] - yv;
            yv += oma * fminf(fmaxf(r, -d), d);
            by[i * 64 + lane] = yv;
        }
        __builtin_amdgcn_sched_barrier(0);

        // 5) repack y -> 16 coalesced dwordx4 stores (1 KB/instr)
        const size_t tb = (size_t)k * TILE;
        #pragma unroll
        for (int g = 0; g < 16; ++g) {
            float4 v = *(const float4*)&by[g * 256 + (lane << 2)];
            *(float4*)(yl + (tb + (size_t)(g * 4)) * CC) = v;
        }
    }
}

extern "C" void kernel_launch(void* const* d_in, const int* in_sizes, int n_in,
                              void* d_out, int out_size, void* d_ws, size_t ws_size,
                              hipStream_t stream) {
    const float* x  = (const float*)d_in[0];
    const float* la = (const float*)d_in[1];
    const float* dl = (const float*)d_in[2];
    float* y = (float*)d_out;

    huber_ema_kernel<<<dim3(256), dim3(64), 0, stream>>>(x, la, dl, y);
}